// Round 1
// baseline (1412.243 us; speedup 1.0000x reference)
//
#include <hip/hip_runtime.h>
#include <hip/hip_bf16.h>

// ---------- types ----------
typedef __attribute__((ext_vector_type(8))) __bf16 bf16x8;
typedef __attribute__((ext_vector_type(4))) float f32x4;

__device__ __forceinline__ unsigned short f2bf(float f) {
    unsigned u = __float_as_uint(f);
    unsigned r = (u + 0x7fffu + ((u >> 16) & 1u)) >> 16;
    return (unsigned short)r;
}

__device__ __forceinline__ void async_load16(const void* g, void* l) {
    __builtin_amdgcn_global_load_lds(
        (const __attribute__((address_space(1))) void*)g,
        (__attribute__((address_space(3))) void*)l, 16, 0, 0);
}

// ---------- constants ----------
// B=32, I=512, O=512, H=W=64, K=3, taps=9, Kdim=4608
// padded NHWC: xp[b][66][66][512] bf16

// ---------- K1: style[b][i] = lin_b[i] + (1/16) * sum_k w[b][k]*lin_w[i][k] ----------
__global__ __launch_bounds__(256) void k_style(const float* __restrict__ w,
                                               const float* __restrict__ lw,
                                               const float* __restrict__ lb,
                                               float* __restrict__ style) {
    int gid = blockIdx.x * 256 + threadIdx.x;   // 16384
    int b = gid >> 9, i = gid & 511;
    const float4* wr = (const float4*)(w + b * 512);
    const float4* lr = (const float4*)(lw + i * 512);
    float s = 0.f;
    for (int k = 0; k < 128; ++k) {
        float4 a = wr[k], c = lr[k];
        s += a.x * c.x + a.y * c.y + a.z * c.z + a.w * c.w;
    }
    style[gid] = s * 0.0625f + lb[i];  // sqrt(2/512) = 1/16
}

// ---------- K2: wbf[o][tap][i] = bf16(conv_w[o][i][tap]); csq[o][i] = sum_t cw^2 ----------
__global__ __launch_bounds__(256) void k_prepw(const float* __restrict__ cw,
                                               unsigned short* __restrict__ wbf,
                                               float* __restrict__ csq) {
    int gid = blockIdx.x * 256 + threadIdx.x;   // 262144
    int o = gid >> 9, i = gid & 511;
    const float* p = cw + (size_t)gid * 9;
    float s = 0.f;
#pragma unroll
    for (int t = 0; t < 9; ++t) {
        float v = p[t];
        s += v * v;
        wbf[(o * 9 + t) * 512 + i] = f2bf(v);
    }
    csq[gid] = s;
}

// ---------- K3: dsc[b][o] = s / sqrt(s^2 * sum_i style^2 * csq + 1e-8), s=sqrt(2/4608) ----------
__global__ __launch_bounds__(256) void k_dscale(const float* __restrict__ style,
                                                const float* __restrict__ csq,
                                                float* __restrict__ dsc) {
    int gid = blockIdx.x * 256 + threadIdx.x;   // 16384
    int b = gid >> 9, o = gid & 511;
    const float4* st = (const float4*)(style + b * 512);
    const float4* cq = (const float4*)(csq + o * 512);
    float s = 0.f;
    for (int k = 0; k < 128; ++k) {
        float4 a = st[k], c = cq[k];
        s += a.x * a.x * c.x + a.y * a.y * c.y + a.z * a.z * c.z + a.w * a.w * c.w;
    }
    const float s2 = 2.0f / 4608.0f;
    float sq = s2 * s + 1e-8f;
    dsc[gid] = sqrtf(s2) * rsqrtf(sq);
}

// ---------- K4: zero the halo of xp ----------
__global__ __launch_bounds__(256) void k_border(unsigned short* __restrict__ xp) {
    int gid = blockIdx.x * 256 + threadIdx.x;   // 32*260*64 = 532480
    int t = gid & 63;
    int cell = gid >> 6;              // 0..8319
    int b = cell / 260, cid = cell - b * 260;
    int r, c;
    if (cid < 66)        { r = 0;  c = cid; }
    else if (cid < 132)  { r = 65; c = cid - 66; }
    else if (cid < 196)  { r = cid - 131; c = 0; }     // rows 1..64
    else                 { r = cid - 195; c = 65; }    // rows 1..64
    uint4* p = (uint4*)(xp + ((size_t)(b * 66 + r) * 66 + c) * 512) + t;
    *p = make_uint4(0u, 0u, 0u, 0u);
}

// ---------- K5: xp[b][y+1][x+1][i] = bf16(style[b][i] * x[b][i][y][x]) ----------
__global__ __launch_bounds__(256) void k_mod_transpose(const float* __restrict__ x,
                                                       const float* __restrict__ style,
                                                       unsigned short* __restrict__ xp) {
    __shared__ unsigned short T[64][66];   // +2 pad breaks bank conflicts
    int bid = blockIdx.x;                  // 32*64*8 = 16384
    int b = bid >> 9;
    int rem = bid & 511;
    int y = rem >> 3, it = rem & 7;
    int i0 = it << 6;
    int t = threadIdx.x;
    int ii = t >> 2, q = t & 3, xq = q << 4;
    float sc = style[b * 512 + i0 + ii];
    const float4* src = (const float4*)(x + (((size_t)(b * 512 + i0 + ii)) * 64 + y) * 64 + xq);
#pragma unroll
    for (int j = 0; j < 4; ++j) {
        float4 v = src[j];
        int xc = xq + j * 4;
        T[ii][xc + 0] = f2bf(v.x * sc);
        T[ii][xc + 1] = f2bf(v.y * sc);
        T[ii][xc + 2] = f2bf(v.z * sc);
        T[ii][xc + 3] = f2bf(v.w * sc);
    }
    __syncthreads();
    int xcol = t >> 2;
    unsigned u[8];
#pragma unroll
    for (int j = 0; j < 8; ++j) {
        unsigned lo = T[q * 16 + 2 * j][xcol];
        unsigned hi = T[q * 16 + 2 * j + 1][xcol];
        u[j] = lo | (hi << 16);
    }
    uint4* dst = (uint4*)(xp + ((size_t)(b * 66 + y + 1) * 66 + (xcol + 1)) * 512 + i0 + q * 16);
    dst[0] = make_uint4(u[0], u[1], u[2], u[3]);
    dst[1] = make_uint4(u[4], u[5], u[6], u[7]);
}

// ---------- K6: implicit-GEMM conv, 128x128 tile, BK=32, bf16 MFMA ----------
__global__ __launch_bounds__(256) void k_conv_gemm(const unsigned short* __restrict__ xp,
                                                   const unsigned short* __restrict__ wbf,
                                                   const float* __restrict__ dsc,
                                                   const float* __restrict__ bias,
                                                   const float* __restrict__ nw,
                                                   const float* __restrict__ noise,
                                                   float* __restrict__ out) {
    __shared__ __align__(16) short As[128 * 32];
    __shared__ __align__(16) short Bs[128 * 32];

    const int tid = threadIdx.x;
    const int lane = tid & 63;
    const int wv = tid >> 6;
    const int bid = blockIdx.x;
    const int mt = bid & 3;          // 4 consecutive blocks share the B-tile (L2 locality)
    const int nt = bid >> 2;         // 0..1023
    const int b  = nt >> 5;          // 0..31
    const int y0 = (nt & 31) << 1;   // 0,2,..,62
    const int o0 = mt << 7;

    // staging mapping: element e = wv*1024 + c*512 + lane*8 -> row=e>>5, col=(lane&3)*8
    const int r0 = (wv << 5) + (lane >> 2);   // c=0 row (0..127)
    const int r1 = r0 + 16;                   // c=1 row
    const int kc = (lane & 3) << 3;           // 0,8,16,24

    const int ry0 = r0 >> 6, xc0 = r0 & 63;
    const int ry1 = r1 >> 6, xc1 = r1 & 63;

    short* asA0 = As + (wv << 10);
    short* asA1 = asA0 + 512;
    short* asB0 = Bs + (wv << 10);
    short* asB1 = asB0 + 512;

    // fragment offsets
    const int mo = (wv & 1) << 6;
    const int no = (wv >> 1) << 6;
    const int lm = lane & 15;
    const int kq = (lane >> 4) << 3;
    int aoff[4], boff[4];
#pragma unroll
    for (int r = 0; r < 4; ++r) aoff[r] = ((mo + r * 16 + lm) << 5) + kq;
#pragma unroll
    for (int c = 0; c < 4; ++c) boff[c] = ((no + c * 16 + lm) << 5) + kq;

    f32x4 acc[4][4];
#pragma unroll
    for (int r = 0; r < 4; ++r)
#pragma unroll
        for (int c = 0; c < 4; ++c) acc[r][c] = (f32x4){0.f, 0.f, 0.f, 0.f};

    const unsigned short* gA0_base = wbf + (size_t)(o0 + r0) * 4608 + kc;
    const unsigned short* gA1_base = wbf + (size_t)(o0 + r1) * 4608 + kc;
    const unsigned short* xpb = xp + (size_t)b * 66 * 66 * 512;

    for (int tap = 0; tap < 9; ++tap) {
        const int ky = tap / 3, kx = tap - ky * 3;
        const unsigned short* gA0 = gA0_base + tap * 512;
        const unsigned short* gA1 = gA1_base + tap * 512;
        const unsigned short* gB0 = xpb + ((size_t)((y0 + ry0 + ky) * 66) + xc0 + kx) * 512 + kc;
        const unsigned short* gB1 = xpb + ((size_t)((y0 + ry1 + ky) * 66) + xc1 + kx) * 512 + kc;
#pragma unroll 1
        for (int i0 = 0; i0 < 16; ++i0) {
            __syncthreads();                 // prev iter's LDS reads done
            async_load16(gA0, asA0);
            async_load16(gA1, asA1);
            async_load16(gB0, asB0);
            async_load16(gB1, asB1);
            gA0 += 32; gA1 += 32; gB0 += 32; gB1 += 32;
            __syncthreads();                 // staging data arrived (vmcnt drain)
            bf16x8 a[4], bb[4];
#pragma unroll
            for (int r = 0; r < 4; ++r) a[r] = *(const bf16x8*)(As + aoff[r]);
#pragma unroll
            for (int c = 0; c < 4; ++c) bb[c] = *(const bf16x8*)(Bs + boff[c]);
#pragma unroll
            for (int r = 0; r < 4; ++r)
#pragma unroll
                for (int c = 0; c < 4; ++c)
                    acc[r][c] = __builtin_amdgcn_mfma_f32_16x16x32_bf16(a[r], bb[c], acc[r][c], 0, 0, 0);
        }
    }

    // epilogue: out = acc * d[b,o] + bias[o] + noise_w[o] * noise
    const int quad = lane >> 4;
#pragma unroll
    for (int r = 0; r < 4; ++r) {
#pragma unroll
        for (int reg = 0; reg < 4; ++reg) {
            const int o = o0 + mo + r * 16 + quad * 4 + reg;
            const float d  = dsc[b * 512 + o];
            const float bi = bias[o];
            const float nwi = nw[o];
#pragma unroll
            for (int c = 0; c < 4; ++c) {
                const int n = no + c * 16 + lm;
                const int y = y0 + (n >> 6);
                const int xx = n & 63;
                const size_t idx = ((size_t)(b * 512 + o) * 64 + y) * 64 + xx;
                out[idx] = acc[r][c][reg] * d + bi + nwi * noise[idx];
            }
        }
    }
}

extern "C" void kernel_launch(void* const* d_in, const int* in_sizes, int n_in,
                              void* d_out, int out_size, void* d_ws, size_t ws_size,
                              hipStream_t stream) {
    (void)in_sizes; (void)n_in; (void)out_size; (void)ws_size;
    const float* x     = (const float*)d_in[0];   // [32,512,64,64]
    const float* w     = (const float*)d_in[1];   // [32,512]
    const float* cw    = (const float*)d_in[2];   // [512,512,3,3]
    const float* lw    = (const float*)d_in[3];   // [512,512]
    const float* lb    = (const float*)d_in[4];   // [512]
    const float* bias  = (const float*)d_in[5];   // [512]
    const float* nwv   = (const float*)d_in[6];   // [512]
    const float* noise = (const float*)d_in[7];   // [32,512,64,64]
    float* out = (float*)d_out;

    char* ws = (char*)d_ws;
    unsigned short* xp  = (unsigned short*)ws;                     // 142,737,408 B
    unsigned short* wbf = (unsigned short*)(ws + 142737408);       //   4,718,592 B
    float* style        = (float*)(ws + 147456000);                //      65,536 B
    float* csq          = (float*)(ws + 147521536);                //   1,048,576 B
    float* dsc          = (float*)(ws + 148570112);                //      65,536 B
    // total: 148,635,648 B

    k_style<<<64, 256, 0, stream>>>(w, lw, lb, style);
    k_prepw<<<1024, 256, 0, stream>>>(cw, wbf, csq);
    k_dscale<<<64, 256, 0, stream>>>(style, csq, dsc);
    k_border<<<2080, 256, 0, stream>>>(xp);
    k_mod_transpose<<<16384, 256, 0, stream>>>(x, style, xp);
    k_conv_gemm<<<4096, 256, 0, stream>>>(xp, wbf, dsc, bias, nwv, noise, out);
}